// Round 1
// baseline (150.958 us; speedup 1.0000x reference)
//
#include <hip/hip_runtime.h>
#include <cstddef>

#define DSZ 4096

// v[i] = g_mu[i] + softplus(g_rho[i]) * epsilon[i]
__global__ void compute_v_kernel(const float* __restrict__ eps,
                                 const float* __restrict__ g_mu,
                                 const float* __restrict__ g_rho,
                                 float* __restrict__ v) {
    int i = blockIdx.x * blockDim.x + threadIdx.x;
    if (i < DSZ) {
        float rho = g_rho[i];
        // numerically stable softplus (rho in [-5,-4] here, but be safe)
        float sp = fmaxf(rho, 0.0f) + log1pf(expf(-fabsf(rho)));
        v[i] = g_mu[i] + sp * eps[i];
    }
}

// Fully-unrolled 6-stage FWHT over a 64-register array (compile-time indices
// only — runtime indexing would spill to scratch).
#define FWHT64(Y) do {                                                  \
    _Pragma("unroll")                                                   \
    for (int s_ = 1; s_ < 64; s_ <<= 1) {                               \
        _Pragma("unroll")                                               \
        for (int r_ = 0; r_ < 64; ++r_) {                               \
            if ((r_ & s_) == 0) {                                       \
                float a_ = Y[r_];                                       \
                float b_ = Y[r_ | s_];                                  \
                Y[r_]      = a_ + b_;                                   \
                Y[r_ | s_] = a_ - b_;                                   \
            }                                                           \
        }                                                               \
    }                                                                   \
} while (0)

// 64x64 in-wave transpose through LDS.
// Current layout <-> new layout are transposes of each other; storage is
// "new-layout contiguous" so reads are ds_read_b128.
// Swizzle: XOR dword-addr bits 2-5 with bits 6-9 -> scalar writes stay 2-way
// (free), stride-64 float4 reads become perfectly bank-balanced.
#define EXCHANGE(Y) do {                                                \
    __syncthreads();  /* WAR: previous reads of lds complete */         \
    _Pragma("unroll")                                                   \
    for (int r_ = 0; r_ < 64; ++r_) {                                   \
        int d_ = r_ * 64 + t;                                           \
        lds[d_ ^ ((r_ & 15) << 2)] = Y[r_];                             \
    }                                                                   \
    __syncthreads();  /* RAW: writes visible */                         \
    _Pragma("unroll")                                                   \
    for (int k_ = 0; k_ < 16; ++k_) {                                   \
        int d_ = t * 64 + k_ * 4;                                       \
        float4 vv_ = *(const float4*)&lds[d_ ^ ((t & 15) << 2)];        \
        Y[4 * k_ + 0] = vv_.x;                                          \
        Y[4 * k_ + 1] = vv_.y;                                          \
        Y[4 * k_ + 2] = vv_.z;                                          \
        Y[4 * k_ + 3] = vv_.w;                                          \
    }                                                                   \
} while (0)

// One wave per row. y[r] register layout:
//   layout A: element i = t*64 + r   (bits 0-5 of i in registers)
//   layout B: element i = r*64 + t   (bits 6-11 of i in registers)
// out[b,:] = s1 .* FWHT( v .* FWHT( s2 .* x[b,:] ) )
__global__ __launch_bounds__(64, 2) void whvi_kernel(
        const float* __restrict__ x,
        const float* __restrict__ s1,
        const float* __restrict__ s2,
        const float* __restrict__ v,
        float* __restrict__ out) {
    __shared__ float lds[DSZ];
    const int t = threadIdx.x;   // 0..63 (one wave)
    const int b = blockIdx.x;    // row index

    const float4* x4  = (const float4*)(x + (size_t)b * DSZ);
    const float4* s24 = (const float4*)s2;
    float y[64];

    // Load x * s2 in layout A (float4-coalesced: wave reads 16KB contiguous)
    #pragma unroll
    for (int k = 0; k < 16; ++k) {
        float4 xv = x4[t * 16 + k];
        float4 sv = s24[t * 16 + k];
        y[4 * k + 0] = xv.x * sv.x;
        y[4 * k + 1] = xv.y * sv.y;
        y[4 * k + 2] = xv.z * sv.z;
        y[4 * k + 3] = xv.w * sv.w;
    }

    FWHT64(y);      // FWHT #1, bits 0-5
    EXCHANGE(y);    // layout A -> B
    FWHT64(y);      // FWHT #1, bits 6-11  (transform #1 complete)

    // y[r] holds element r*64 + t ; multiply by v (coalesced, L2-resident)
    #pragma unroll
    for (int r = 0; r < 64; ++r) {
        y[r] *= v[r * 64 + t];
    }

    FWHT64(y);      // FWHT #2, bits 6-11
    EXCHANGE(y);    // layout B -> A
    FWHT64(y);      // FWHT #2, bits 0-5  (transform #2 complete)

    // Multiply by s1 and store (float4-coalesced)
    const float4* s14 = (const float4*)s1;
    float4* o4 = (float4*)(out + (size_t)b * DSZ);
    #pragma unroll
    for (int k = 0; k < 16; ++k) {
        float4 sv = s14[t * 16 + k];
        float4 ov;
        ov.x = y[4 * k + 0] * sv.x;
        ov.y = y[4 * k + 1] * sv.y;
        ov.z = y[4 * k + 2] * sv.z;
        ov.w = y[4 * k + 3] * sv.w;
        o4[t * 16 + k] = ov;
    }
}

extern "C" void kernel_launch(void* const* d_in, const int* in_sizes, int n_in,
                              void* d_out, int out_size, void* d_ws, size_t ws_size,
                              hipStream_t stream) {
    // setup_inputs order: x, epsilon, s1, s2, g_mu, g_rho
    const float* x     = (const float*)d_in[0];
    const float* eps   = (const float*)d_in[1];
    const float* s1    = (const float*)d_in[2];
    const float* s2    = (const float*)d_in[3];
    const float* g_mu  = (const float*)d_in[4];
    const float* g_rho = (const float*)d_in[5];
    float* out = (float*)d_out;
    float* v   = (float*)d_ws;   // 16 KB scratch for v

    compute_v_kernel<<<DSZ / 256, 256, 0, stream>>>(eps, g_mu, g_rho, v);
    whvi_kernel<<<4096, 64, 0, stream>>>(x, s1, s2, v, out);
}

// Round 4
// 129.106 us; speedup vs baseline: 1.1693x; 1.1693x over previous
//
#include <hip/hip_runtime.h>
#include <cstddef>

#define DSZ 4096

// v[i] = g_mu[i] + softplus(g_rho[i]) * epsilon[i]
__global__ void compute_v_kernel(const float* __restrict__ eps,
                                 const float* __restrict__ g_mu,
                                 const float* __restrict__ g_rho,
                                 float* __restrict__ v) {
    int i = blockIdx.x * blockDim.x + threadIdx.x;
    if (i < DSZ) {
        float rho = g_rho[i];
        float sp = fmaxf(rho, 0.0f) + log1pf(expf(-fabsf(rho)));
        v[i] = g_mu[i] + sp * eps[i];
    }
}

// Global LDS swizzle (involution, bijective): XOR dword-addr bits 2-5 with
// bits 6-9. Makes all three access patterns below bank-conflict-free:
//  A (float4 @ 4T+1024j): 8 lanes per aligned 4-bank group = inherent min
//  B (scalar, stride-4):  32 distinct banks per instr (mask constant/thread)
//  C (scalar, stride-64): consecutive lanes, mask constant per instr
__device__ __forceinline__ int swz(int a) {
    return a ^ (((a >> 6) & 15) << 2);
}

// 4-stage FWHT over 16 registers, compile-time indices only.
#define FWHT16(Y) do {                                                  \
    _Pragma("unroll")                                                   \
    for (int s_ = 1; s_ < 16; s_ <<= 1) {                               \
        _Pragma("unroll")                                               \
        for (int r_ = 0; r_ < 16; ++r_) {                               \
            if ((r_ & s_) == 0) {                                       \
                float a_ = Y[r_];                                       \
                float b_ = Y[r_ | s_];                                  \
                Y[r_]      = a_ + b_;                                   \
                Y[r_ | s_] = a_ - b_;                                   \
            }                                                           \
        }                                                               \
    }                                                                   \
} while (0)

// One 256-thread block per row; 16 floats/thread. Register-resident element
// bits per layout (FWHT stages commute, so any bit order works):
//   layout A: i = 4*T + (r&3) + 1024*(r>>2)     regs = bits {0,1,10,11}
//   layout B: i = (T&3) + 4*r + 64*(T>>2)       regs = bits {2,3,4,5}
//   layout C: i = (T&63) + 64*r + 1024*(T>>6)   regs = bits {6,7,8,9}
// out[b,:] = s1 .* FWHT( v .* FWHT( s2 .* x[b,:] ) )
__global__ __launch_bounds__(256, 8) void whvi_kernel(
        const float* __restrict__ x,
        const float* __restrict__ s1,
        const float* __restrict__ s2,
        const float* __restrict__ v,
        float* __restrict__ out) {
    __shared__ float lds[DSZ];
    const int T = threadIdx.x;
    const int b = blockIdx.x;
    float y[16];

    // ---- load x * s2 in layout A (lane-contiguous float4 = archetype) ----
    const float4* x4  = (const float4*)(x + (size_t)b * DSZ);
    const float4* s24 = (const float4*)s2;
    #pragma unroll
    for (int j = 0; j < 4; ++j) {
        float4 xv = x4[T + 256 * j];
        float4 sv = s24[T + 256 * j];
        y[4 * j + 0] = xv.x * sv.x;
        y[4 * j + 1] = xv.y * sv.y;
        y[4 * j + 2] = xv.z * sv.z;
        y[4 * j + 3] = xv.w * sv.w;
    }

    FWHT16(y);                       // FWHT#1: bits 0,1,10,11

    // ---- exchange A -> B ----
    #pragma unroll
    for (int j = 0; j < 4; ++j) {
        *(float4*)&lds[swz(4 * T + 1024 * j)] =
            make_float4(y[4 * j], y[4 * j + 1], y[4 * j + 2], y[4 * j + 3]);
    }
    __syncthreads();
    #pragma unroll
    for (int r = 0; r < 16; ++r)
        y[r] = lds[swz((T & 3) + 4 * r + 64 * (T >> 2))];

    FWHT16(y);                       // FWHT#1: bits 2-5

    // ---- exchange B -> C (each thread rewrites exactly the slots it just
    //      read, so no barrier needed between the read above and this write)
    #pragma unroll
    for (int r = 0; r < 16; ++r)
        lds[swz((T & 3) + 4 * r + 64 * (T >> 2))] = y[r];
    __syncthreads();
    #pragma unroll
    for (int r = 0; r < 16; ++r)
        y[r] = lds[swz((T & 63) + 64 * r + 1024 * (T >> 6))];

    FWHT16(y);                       // FWHT#1: bits 6-9  (transform 1 done)

    // ---- multiply by v (coalesced 256B runs, L2-resident) ----
    const float* vb = v + (T & 63) + 1024 * (T >> 6);
    #pragma unroll
    for (int r = 0; r < 16; ++r)
        y[r] *= vb[64 * r];

    FWHT16(y);                       // FWHT#2: bits 6-9

    // ---- exchange C -> B ----
    #pragma unroll
    for (int r = 0; r < 16; ++r)
        lds[swz((T & 63) + 64 * r + 1024 * (T >> 6))] = y[r];
    __syncthreads();
    #pragma unroll
    for (int r = 0; r < 16; ++r)
        y[r] = lds[swz((T & 3) + 4 * r + 64 * (T >> 2))];

    FWHT16(y);                       // FWHT#2: bits 2-5

    // ---- exchange B -> A ----
    #pragma unroll
    for (int r = 0; r < 16; ++r)
        lds[swz((T & 3) + 4 * r + 64 * (T >> 2))] = y[r];
    __syncthreads();
    #pragma unroll
    for (int j = 0; j < 4; ++j) {
        float4 t4 = *(const float4*)&lds[swz(4 * T + 1024 * j)];
        y[4 * j + 0] = t4.x;
        y[4 * j + 1] = t4.y;
        y[4 * j + 2] = t4.z;
        y[4 * j + 3] = t4.w;
    }

    FWHT16(y);                       // FWHT#2: bits 0,1,10,11 (done)

    // ---- scale by s1, store (lane-contiguous float4) ----
    const float4* s14 = (const float4*)s1;
    float4* o4 = (float4*)(out + (size_t)b * DSZ);
    #pragma unroll
    for (int j = 0; j < 4; ++j) {
        float4 sv = s14[T + 256 * j];
        float4 ov;
        ov.x = y[4 * j + 0] * sv.x;
        ov.y = y[4 * j + 1] * sv.y;
        ov.z = y[4 * j + 2] * sv.z;
        ov.w = y[4 * j + 3] * sv.w;
        o4[T + 256 * j] = ov;
    }
}

extern "C" void kernel_launch(void* const* d_in, const int* in_sizes, int n_in,
                              void* d_out, int out_size, void* d_ws, size_t ws_size,
                              hipStream_t stream) {
    // setup_inputs order: x, epsilon, s1, s2, g_mu, g_rho
    const float* x     = (const float*)d_in[0];
    const float* eps   = (const float*)d_in[1];
    const float* s1    = (const float*)d_in[2];
    const float* s2    = (const float*)d_in[3];
    const float* g_mu  = (const float*)d_in[4];
    const float* g_rho = (const float*)d_in[5];
    float* out = (float*)d_out;
    float* v   = (float*)d_ws;   // 16 KB scratch

    compute_v_kernel<<<DSZ / 256, 256, 0, stream>>>(eps, g_mu, g_rho, v);
    whvi_kernel<<<4096, 256, 0, stream>>>(x, s1, s2, v, out);
}